// Round 2
// baseline (1085.516 us; speedup 1.0000x reference)
//
#include <hip/hip_runtime.h>
#include <hip/hip_bf16.h>

// Problem constants (from reference)
#define BB 4096
#define VV 200
#define FF 4
#define GG 80
#define RR 16
#define NLIG 7
// f32(2*pi) = 0x40C90FDB; f32(2*pi/16) = 0x3EC90FDB; 16*ANG_STEP == TWO_PI_F exactly
#define TWO_PI_F 6.2831853071795864769f
#define ANG_STEP 0.39269908169872414f
#define INV_ANG_STEP 2.5464790894703255f
#define LOG2E_F 1.4426950408889634f

// ---------------------------------------------------------------------------
// Kernel A: per-sample b. Gaussian agg over (f,g,r) via geometric recurrence
// (4 exps per (v,thread) instead of 16; 20 B/lane/v LDS instead of 72),
// conv GEMV + relu + max over rotations, fc1 + relu.
// One block per b, 320 threads = (f,g).
// ---------------------------------------------------------------------------
__global__ __launch_bounds__(320) void masif_main(
    const float* __restrict__ xin,      // [B,V,F]
    const float* __restrict__ rho,      // [B,V]
    const float* __restrict__ theta,    // [B,V]
    const float* __restrict__ mask,     // [B,V]
    const float* __restrict__ mu_rho,   // [F,G]
    const float* __restrict__ mu_theta, // [F,G]
    const float* __restrict__ sigma_rho,   // [F,G]
    const float* __restrict__ sigma_theta, // [F,G]
    const float* __restrict__ conv_W,   // [F,G,G]
    const float* __restrict__ conv_b,   // [F,G]
    const float* __restrict__ fc1_W,    // [G, F*G]
    const float* __restrict__ fc1_b,    // [G]
    float* __restrict__ xbuf)           // [B,G] out
{
    const int b = blockIdx.x;
    const int t = threadIdx.x;
    const int f = t / GG;   // 0..3
    const int g = t % GG;   // 0..79

    __shared__ float pack_s[VV][8];    // {rho, th, a0, rw_bits, mx0..3}  6.4 KB
    __shared__ float aggL[FF][RR][GG]; // 20.5 KB
    __shared__ float desc_s[FF * GG];  // 1.3 KB
    __shared__ float hp_s[FF][GG];     // 1.3 KB

    // ---- stage per-vertex data: decompose wrapped angles ----
    // wrap(th + r*Dlt) == a0 + ((j0 + r) & 15)*Dlt,  a0 = th - j0*Dlt
    for (int v = t; v < VV; v += 320) {
        const int idx = b * VV + v;
        float th = theta[idx];
        float m  = mask[idx];
        float rh = rho[idx];
        int j0 = (int)(th * INV_ANG_STEP);
        j0 = min(j0, RR - 1);                       // guard th ~ 2*pi rounding
        float a0 = fmaf(-(float)j0, ANG_STEP, th);  // th mod Dlt
        int rw = RR - j0;                           // reset point, in [1,16]
        float4 xv = *reinterpret_cast<const float4*>(&xin[idx * 4]);
        pack_s[v][0] = rh;
        pack_s[v][1] = th;
        pack_s[v][2] = a0;
        pack_s[v][3] = __int_as_float(rw);
        pack_s[v][4] = m * xv.x;
        pack_s[v][5] = m * xv.y;
        pack_s[v][6] = m * xv.z;
        pack_s[v][7] = m * xv.w;
    }

    // per-(f,g) parameters (exp2-based: LOG2E folded into the scale consts)
    const float mr  = mu_rho[f * GG + g];
    const float mt  = mu_theta[f * GG + g];
    const float sr  = sigma_rho[f * GG + g];
    const float st  = sigma_theta[f * GG + g];
    const float nisr2 = -LOG2E_F / (sr * sr + 1e-5f);
    const float nist2 = -LOG2E_F / (st * st + 1e-5f);
    const float c1 = 2.0f * ANG_STEP * nist2;            // u(x)=2^(c1*x+c2)
    const float c2 = ANG_STEP * ANG_STEP * nist2;
    const float w  = exp2f(2.0f * ANG_STEP * ANG_STEP * nist2); // u ratio

    __syncthreads();

    // ---- gaussian aggregation via geometric recurrence ----
    float acc[RR];
    #pragma unroll
    for (int r = 0; r < RR; ++r) acc[r] = 0.0f;

    for (int v = 0; v < VV; ++v) {
        const float4 p = *reinterpret_cast<const float4*>(&pack_s[v][0]);
        const float s  = pack_s[v][4 + f];
        const int rw   = __builtin_amdgcn_readfirstlane(__float_as_int(p.w));
        const float d   = p.x - mr;
        const float ar2 = (d * d) * nisr2;        // rho part folded into exps
        const float xa  = p.y - mt;               // angle at r=0 (j=j0): == th
        const float xz  = p.z - mt;               // angle at j=0:      == a0
        float e        = exp2f(fmaf(xa * xa, nist2, ar2));
        float u        = exp2f(fmaf(xa, c1, c2));
        const float ez = exp2f(fmaf(xz * xz, nist2, ar2));
        const float uz = exp2f(fmaf(xz, c1, c2));
        #pragma unroll
        for (int r = 0; r < RR; ++r) {
            acc[r] = fmaf(e, s, acc[r]);
            float en = e * u;
            float un = u * w;
            bool res = (r + 1 == rw);   // block-uniform -> scalar cmp
            e = res ? ez : en;
            u = res ? uz : un;
        }
    }

    #pragma unroll
    for (int r = 0; r < RR; ++r) aggL[f][r][g] = acc[r];

    __syncthreads();

    // ---- conv GEMV + relu + max over rotations: thread = (f, j=g) ----
    float racc[RR];
    const float cb = conv_b[f * GG + g];
    #pragma unroll
    for (int r = 0; r < RR; ++r) racc[r] = cb;
    for (int g4 = 0; g4 < GG; g4 += 4) {
        const float w0 = conv_W[(f * GG + g4 + 0) * GG + g];
        const float w1 = conv_W[(f * GG + g4 + 1) * GG + g];
        const float w2 = conv_W[(f * GG + g4 + 2) * GG + g];
        const float w3 = conv_W[(f * GG + g4 + 3) * GG + g];
        #pragma unroll
        for (int r = 0; r < RR; ++r) {
            const float4 a4 = *reinterpret_cast<const float4*>(&aggL[f][r][g4]);
            float x = racc[r];
            x = fmaf(a4.x, w0, x);
            x = fmaf(a4.y, w1, x);
            x = fmaf(a4.z, w2, x);
            x = fmaf(a4.w, w3, x);
            racc[r] = x;
        }
    }
    float mxr = racc[0];
    #pragma unroll
    for (int r = 1; r < RR; ++r) mxr = fmaxf(mxr, racc[r]);
    desc_s[f * GG + g] = fmaxf(mxr, 0.0f);

    __syncthreads();

    // ---- fc1 + relu (80 outputs, dot over 320; 4-way k-split, all threads) --
    {
        const int p  = f;       // k-partial index 0..3
        const int jj = g;       // output index
        const float* wrow = &fc1_W[jj * (FF * GG) + p * GG];
        const float* drow = &desc_s[p * GG];
        float a = 0.0f;
        #pragma unroll 4
        for (int k = 0; k < GG; ++k) a = fmaf(drow[k], wrow[k], a);
        hp_s[p][jj] = a;
    }
    __syncthreads();
    if (t < GG) {
        float a1 = ((hp_s[0][t] + hp_s[1][t]) + (hp_s[2][t] + hp_s[3][t])) + fc1_b[t];
        xbuf[b * GG + t] = fmaxf(a1, 0.0f);
    }
}

// ---------------------------------------------------------------------------
// Kernel B: partial gram. 64 blocks x 64 samples each; 256 threads own 5x5
// tiles of the 80x80 outer-product accumulation. Deterministic.
// ---------------------------------------------------------------------------
__global__ __launch_bounds__(256) void gram_partial(
    const float* __restrict__ xbuf,   // [B,G]
    float* __restrict__ gpart)        // [64, G*G]
{
    const int blk = blockIdx.x;   // 0..63
    const int t = threadIdx.x;
    __shared__ float xs[64][GG];

    for (int i = t; i < 64 * GG; i += 256) {
        int bb = i / GG, jj = i % GG;
        xs[bb][jj] = xbuf[(blk * 64 + bb) * GG + jj];
    }
    __syncthreads();

    const int ti = t / 16, tj = t % 16;   // 16x16 grid of 5x5 tiles
    float acc[5][5];
    #pragma unroll
    for (int u = 0; u < 5; ++u)
        #pragma unroll
        for (int w = 0; w < 5; ++w) acc[u][w] = 0.0f;

    for (int bb = 0; bb < 64; ++bb) {
        float xi[5], xj[5];
        #pragma unroll
        for (int u = 0; u < 5; ++u) { xi[u] = xs[bb][ti * 5 + u]; xj[u] = xs[bb][tj * 5 + u]; }
        #pragma unroll
        for (int u = 0; u < 5; ++u)
            #pragma unroll
            for (int w = 0; w < 5; ++w)
                acc[u][w] = fmaf(xi[u], xj[w], acc[u][w]);
    }

    #pragma unroll
    for (int u = 0; u < 5; ++u)
        #pragma unroll
        for (int w = 0; w < 5; ++w)
            gpart[blk * (GG * GG) + (ti * 5 + u) * GG + (tj * 5 + w)] = acc[u][w];
}

// ---------------------------------------------------------------------------
// Kernel C: reduce gram partials (ordered -> deterministic), fc2+relu, fco.
// ---------------------------------------------------------------------------
__global__ __launch_bounds__(256) void final_head(
    const float* __restrict__ gpart,  // [64, G*G]
    const float* __restrict__ fc2_W,  // [64, G*G]
    const float* __restrict__ fc2_b,  // [64]
    const float* __restrict__ fco_W,  // [NLIG, 64]
    const float* __restrict__ fco_b,  // [NLIG]
    float* __restrict__ out)          // [NLIG]
{
    const int t = threadIdx.x;
    __shared__ float gram[GG * GG];   // 25.6 KB
    __shared__ float hp[4][64];
    __shared__ float h[64];

    for (int i = t; i < GG * GG; i += 256) {
        float s = 0.0f;
        for (int p = 0; p < 64; ++p) s += gpart[p * (GG * GG) + i];
        gram[i] = s * (1.0f / 4096.0f);
    }
    __syncthreads();

    {
        const int jj = t & 63, part = t >> 6;    // 4 partial splits over k
        float a = 0.0f;
        const int k0 = part * 1600, k1 = k0 + 1600;
        for (int k = k0; k < k1; ++k)
            a = fmaf(gram[k], fc2_W[jj * (GG * GG) + k], a);
        hp[part][jj] = a;
    }
    __syncthreads();
    if (t < 64)
        h[t] = fmaxf(hp[0][t] + hp[1][t] + hp[2][t] + hp[3][t] + fc2_b[t], 0.0f);
    __syncthreads();

    if (t < NLIG) {
        float a = fco_b[t];
        #pragma unroll
        for (int jj = 0; jj < 64; ++jj)
            a = fmaf(h[jj], fco_W[t * 64 + jj], a);
        out[t] = a;
    }
}

// ---------------------------------------------------------------------------
extern "C" void kernel_launch(void* const* d_in, const int* in_sizes, int n_in,
                              void* d_out, int out_size, void* d_ws, size_t ws_size,
                              hipStream_t stream) {
    const float* input_feat  = (const float*)d_in[0];
    const float* rho         = (const float*)d_in[1];
    const float* theta       = (const float*)d_in[2];
    const float* mask        = (const float*)d_in[3];
    const float* mu_rho      = (const float*)d_in[4];
    const float* mu_theta    = (const float*)d_in[5];
    const float* sigma_rho   = (const float*)d_in[6];
    const float* sigma_theta = (const float*)d_in[7];
    const float* conv_W      = (const float*)d_in[8];
    const float* conv_b      = (const float*)d_in[9];
    const float* fc1_W       = (const float*)d_in[10];
    const float* fc1_b       = (const float*)d_in[11];
    const float* fc2_W       = (const float*)d_in[12];
    const float* fc2_b       = (const float*)d_in[13];
    const float* fco_W       = (const float*)d_in[14];
    const float* fco_b       = (const float*)d_in[15];

    float* xbuf  = (float*)d_ws;                                    // [B,G]  1.31 MB
    float* gpart = (float*)((char*)d_ws + (size_t)BB * GG * 4);     // [64,G*G] 1.64 MB

    masif_main<<<BB, 320, 0, stream>>>(input_feat, rho, theta, mask,
                                       mu_rho, mu_theta, sigma_rho, sigma_theta,
                                       conv_W, conv_b, fc1_W, fc1_b, xbuf);
    gram_partial<<<64, 256, 0, stream>>>(xbuf, gpart);
    final_head<<<1, 256, 0, stream>>>(gpart, fc2_W, fc2_b, fco_W, fco_b,
                                      (float*)d_out);
}

// Round 3
// 913.273 us; speedup vs baseline: 1.1886x; 1.1886x over previous
//
#include <hip/hip_runtime.h>
#include <hip/hip_bf16.h>

// Problem constants (from reference)
#define BB 4096
#define VV 200
#define FF 4
#define GG 80
#define RR 16
#define NLIG 7
// f32(2*pi) = 0x40C90FDB; ANG_STEP = f32(2*pi)/16 exactly; 16*ANG_STEP == TWO_PI_F exactly
#define TWO_PI_F 6.2831853071795864769f
#define ANG_STEP 0.39269908169872414f
#define INV_ANG_STEP 2.5464790894703255f
#define LOG2E_F 1.4426950408889634f

__device__ __forceinline__ float fexp2(float x) {
#if __has_builtin(__builtin_amdgcn_exp2f)
    return __builtin_amdgcn_exp2f(x);   // raw v_exp_f32, 1 instr
#else
    return exp2f(x);
#endif
}

// Per-vertex inner step for uniform j0 = J0.
// Gaussian at rotation r: theta_r = wrap(th + r*ANG_STEP) = a0 + j*ANG_STEP,
// j = (J0 + r) & 15.  e_r = M * B^m * K_m with m the offset from the anchor:
//   chain 1 (r = 0 .. 15-J0):  anchor th (j=J0), m = r
//   chain 2 (r = 16-J0 .. 15): anchor a0 (j=0),  m = j = r-(16-J0)
// K_m = 2^(nist2 * ANG_STEP^2 * m^2) is a per-thread constant table ->
// all K indices are compile-time constants inside this template.
template<int J0>
__device__ __forceinline__ void vstep(float (&acc)[RR], const float (&K)[RR],
                                      float M1, float B1, float M2, float B2) {
    float t = M1;
    #pragma unroll
    for (int r = 0; r < RR - J0; ++r) {
        acc[r] = fmaf(t, K[r], acc[r]);
        t *= B1;
    }
    if constexpr (J0 > 0) {
        float t2 = M2;
        #pragma unroll
        for (int j = 0; j < J0; ++j) {
            acc[RR - J0 + j] = fmaf(t2, K[j], acc[RR - J0 + j]);
            t2 *= B2;
        }
    }
}

// ---------------------------------------------------------------------------
// Kernel A: per-sample b. Gaussian agg over (f,g,r) via geometric chain with
// static K table (mul+fma per (v,r)), conv GEMV + relu + max over rotations,
// fc1 + relu.  One block per b, 320 threads = (f,g).
// ---------------------------------------------------------------------------
__global__ __launch_bounds__(320) void masif_main(
    const float* __restrict__ xin,      // [B,V,F]
    const float* __restrict__ rho,      // [B,V]
    const float* __restrict__ theta,    // [B,V]
    const float* __restrict__ mask,     // [B,V]
    const float* __restrict__ mu_rho,   // [F,G]
    const float* __restrict__ mu_theta, // [F,G]
    const float* __restrict__ sigma_rho,   // [F,G]
    const float* __restrict__ sigma_theta, // [F,G]
    const float* __restrict__ conv_W,   // [F,G,G]
    const float* __restrict__ conv_b,   // [F,G]
    const float* __restrict__ fc1_W,    // [G, F*G]
    const float* __restrict__ fc1_b,    // [G]
    float* __restrict__ xbuf)           // [B,G] out
{
    const int b = blockIdx.x;
    const int t = threadIdx.x;
    const int f = t / GG;   // 0..3
    const int g = t % GG;   // 0..79

    __shared__ float pack_s[VV][8];    // {rho, th, a0, j0_bits, mx0..3}  6.4 KB
    __shared__ float aggL[FF][RR][GG]; // 20.5 KB
    __shared__ float desc_s[FF * GG];  // 1.3 KB
    __shared__ float hp_s[FF][GG];     // 1.3 KB

    // ---- stage per-vertex data: decompose wrapped angles ----
    // wrap(th + r*Dlt) == a0 + ((j0 + r) & 15)*Dlt,  a0 = th - j0*Dlt
    for (int v = t; v < VV; v += 320) {
        const int idx = b * VV + v;
        float th = theta[idx];
        float m  = mask[idx];
        float rh = rho[idx];
        int j0 = (int)(th * INV_ANG_STEP);
        if (j0 > RR - 1) j0 = RR - 1;               // guard th ~ 2*pi rounding
        float a0 = fmaf(-(float)j0, ANG_STEP, th);  // th mod Dlt
        float4 xv = *reinterpret_cast<const float4*>(&xin[idx * 4]);
        *reinterpret_cast<float4*>(&pack_s[v][0]) =
            make_float4(rh, th, a0, __int_as_float(j0));
        *reinterpret_cast<float4*>(&pack_s[v][4]) =
            make_float4(m * xv.x, m * xv.y, m * xv.z, m * xv.w);
    }

    // per-(f,g) parameters (exp2-based: LOG2E folded into the scale consts)
    const float mr  = mu_rho[f * GG + g];
    const float mt  = mu_theta[f * GG + g];
    const float sr  = sigma_rho[f * GG + g];
    const float st  = sigma_theta[f * GG + g];
    const float nisr2 = -LOG2E_F / (sr * sr + 1e-5f);
    const float nist2 = -LOG2E_F / (st * st + 1e-5f);
    const float c1 = 2.0f * ANG_STEP * nist2;       // B(x) = 2^(c1*x)

    // static quadratic table K[m] = 2^(nist2 * Dlt^2 * m^2)  (16 regs)
    float K[RR];
    #pragma unroll
    for (int m = 0; m < RR; ++m)
        K[m] = fexp2(nist2 * (ANG_STEP * ANG_STEP) * (float)(m * m));

    __syncthreads();

    // ---- gaussian aggregation: 1 mul + 1 fma per (v,r) ----
    float acc[RR];
    #pragma unroll
    for (int r = 0; r < RR; ++r) acc[r] = 0.0f;

    for (int v = 0; v < VV; ++v) {
        const float4 p = *reinterpret_cast<const float4*>(&pack_s[v][0]);
        const float s  = pack_s[v][4 + f];
        const int j0   = __builtin_amdgcn_readfirstlane(__float_as_int(p.w));
        const float dr  = p.x - mr;
        const float ar2 = (dr * dr) * nisr2;        // rho part (log2 units)
        const float y   = p.y - mt;                 // anchor 1: th   (j = j0)
        const float x   = p.z - mt;                 // anchor 2: a0   (j = 0)
        const float M1 = fexp2(fmaf(y * y, nist2, ar2)) * s;
        const float B1 = fexp2(y * c1);
        const float M2 = fexp2(fmaf(x * x, nist2, ar2)) * s;
        const float B2 = fexp2(x * c1);
        switch (j0) {
#define VS_CASE(c) case c: vstep<c>(acc, K, M1, B1, M2, B2); break;
            VS_CASE(0)  VS_CASE(1)  VS_CASE(2)  VS_CASE(3)
            VS_CASE(4)  VS_CASE(5)  VS_CASE(6)  VS_CASE(7)
            VS_CASE(8)  VS_CASE(9)  VS_CASE(10) VS_CASE(11)
            VS_CASE(12) VS_CASE(13) VS_CASE(14) VS_CASE(15)
#undef VS_CASE
            default: __builtin_unreachable();
        }
    }

    #pragma unroll
    for (int r = 0; r < RR; ++r) aggL[f][r][g] = acc[r];

    __syncthreads();

    // ---- conv GEMV + relu + max over rotations: thread = (f, j=g) ----
    float racc[RR];
    const float cb = conv_b[f * GG + g];
    #pragma unroll
    for (int r = 0; r < RR; ++r) racc[r] = cb;
    for (int g4 = 0; g4 < GG; g4 += 4) {
        const float w0 = conv_W[(f * GG + g4 + 0) * GG + g];
        const float w1 = conv_W[(f * GG + g4 + 1) * GG + g];
        const float w2 = conv_W[(f * GG + g4 + 2) * GG + g];
        const float w3 = conv_W[(f * GG + g4 + 3) * GG + g];
        #pragma unroll
        for (int r = 0; r < RR; ++r) {
            const float4 a4 = *reinterpret_cast<const float4*>(&aggL[f][r][g4]);
            float xx = racc[r];
            xx = fmaf(a4.x, w0, xx);
            xx = fmaf(a4.y, w1, xx);
            xx = fmaf(a4.z, w2, xx);
            xx = fmaf(a4.w, w3, xx);
            racc[r] = xx;
        }
    }
    float mxr = racc[0];
    #pragma unroll
    for (int r = 1; r < RR; ++r) mxr = fmaxf(mxr, racc[r]);
    desc_s[f * GG + g] = fmaxf(mxr, 0.0f);

    __syncthreads();

    // ---- fc1 + relu (80 outputs, dot over 320; 4-way k-split, all threads) --
    {
        const int p  = f;       // k-partial index 0..3
        const int jj = g;       // output index
        const float* wrow = &fc1_W[jj * (FF * GG) + p * GG];
        const float* drow = &desc_s[p * GG];
        float a = 0.0f;
        #pragma unroll 4
        for (int k = 0; k < GG; ++k) a = fmaf(drow[k], wrow[k], a);
        hp_s[p][jj] = a;
    }
    __syncthreads();
    if (t < GG) {
        float a1 = ((hp_s[0][t] + hp_s[1][t]) + (hp_s[2][t] + hp_s[3][t])) + fc1_b[t];
        xbuf[b * GG + t] = fmaxf(a1, 0.0f);
    }
}

// ---------------------------------------------------------------------------
// Kernel B: partial gram. 64 blocks x 64 samples each; 256 threads own 5x5
// tiles of the 80x80 outer-product accumulation. Deterministic.
// ---------------------------------------------------------------------------
__global__ __launch_bounds__(256) void gram_partial(
    const float* __restrict__ xbuf,   // [B,G]
    float* __restrict__ gpart)        // [64, G*G]
{
    const int blk = blockIdx.x;   // 0..63
    const int t = threadIdx.x;
    __shared__ float xs[64][GG];

    for (int i = t; i < 64 * GG; i += 256) {
        int bb = i / GG, jj = i % GG;
        xs[bb][jj] = xbuf[(blk * 64 + bb) * GG + jj];
    }
    __syncthreads();

    const int ti = t / 16, tj = t % 16;   // 16x16 grid of 5x5 tiles
    float acc[5][5];
    #pragma unroll
    for (int u = 0; u < 5; ++u)
        #pragma unroll
        for (int w = 0; w < 5; ++w) acc[u][w] = 0.0f;

    for (int bb = 0; bb < 64; ++bb) {
        float xi[5], xj[5];
        #pragma unroll
        for (int u = 0; u < 5; ++u) { xi[u] = xs[bb][ti * 5 + u]; xj[u] = xs[bb][tj * 5 + u]; }
        #pragma unroll
        for (int u = 0; u < 5; ++u)
            #pragma unroll
            for (int w = 0; w < 5; ++w)
                acc[u][w] = fmaf(xi[u], xj[w], acc[u][w]);
    }

    #pragma unroll
    for (int u = 0; u < 5; ++u)
        #pragma unroll
        for (int w = 0; w < 5; ++w)
            gpart[blk * (GG * GG) + (ti * 5 + u) * GG + (tj * 5 + w)] = acc[u][w];
}

// ---------------------------------------------------------------------------
// Kernel C: reduce gram partials (ordered -> deterministic), fc2+relu, fco.
// ---------------------------------------------------------------------------
__global__ __launch_bounds__(256) void final_head(
    const float* __restrict__ gpart,  // [64, G*G]
    const float* __restrict__ fc2_W,  // [64, G*G]
    const float* __restrict__ fc2_b,  // [64]
    const float* __restrict__ fco_W,  // [NLIG, 64]
    const float* __restrict__ fco_b,  // [NLIG]
    float* __restrict__ out)          // [NLIG]
{
    const int t = threadIdx.x;
    __shared__ float gram[GG * GG];   // 25.6 KB
    __shared__ float hp[4][64];
    __shared__ float h[64];

    for (int i = t; i < GG * GG; i += 256) {
        float s = 0.0f;
        for (int p = 0; p < 64; ++p) s += gpart[p * (GG * GG) + i];
        gram[i] = s * (1.0f / 4096.0f);
    }
    __syncthreads();

    {
        const int jj = t & 63, part = t >> 6;    // 4 partial splits over k
        float a = 0.0f;
        const int k0 = part * 1600, k1 = k0 + 1600;
        for (int k = k0; k < k1; ++k)
            a = fmaf(gram[k], fc2_W[jj * (GG * GG) + k], a);
        hp[part][jj] = a;
    }
    __syncthreads();
    if (t < 64)
        h[t] = fmaxf(hp[0][t] + hp[1][t] + hp[2][t] + hp[3][t] + fc2_b[t], 0.0f);
    __syncthreads();

    if (t < NLIG) {
        float a = fco_b[t];
        #pragma unroll
        for (int jj = 0; jj < 64; ++jj)
            a = fmaf(h[jj], fco_W[t * 64 + jj], a);
        out[t] = a;
    }
}

// ---------------------------------------------------------------------------
extern "C" void kernel_launch(void* const* d_in, const int* in_sizes, int n_in,
                              void* d_out, int out_size, void* d_ws, size_t ws_size,
                              hipStream_t stream) {
    const float* input_feat  = (const float*)d_in[0];
    const float* rho         = (const float*)d_in[1];
    const float* theta       = (const float*)d_in[2];
    const float* mask        = (const float*)d_in[3];
    const float* mu_rho      = (const float*)d_in[4];
    const float* mu_theta    = (const float*)d_in[5];
    const float* sigma_rho   = (const float*)d_in[6];
    const float* sigma_theta = (const float*)d_in[7];
    const float* conv_W      = (const float*)d_in[8];
    const float* conv_b      = (const float*)d_in[9];
    const float* fc1_W       = (const float*)d_in[10];
    const float* fc1_b       = (const float*)d_in[11];
    const float* fc2_W       = (const float*)d_in[12];
    const float* fc2_b       = (const float*)d_in[13];
    const float* fco_W       = (const float*)d_in[14];
    const float* fco_b       = (const float*)d_in[15];

    float* xbuf  = (float*)d_ws;                                    // [B,G]  1.31 MB
    float* gpart = (float*)((char*)d_ws + (size_t)BB * GG * 4);     // [64,G*G] 1.64 MB

    masif_main<<<BB, 320, 0, stream>>>(input_feat, rho, theta, mask,
                                       mu_rho, mu_theta, sigma_rho, sigma_theta,
                                       conv_W, conv_b, fc1_W, fc1_b, xbuf);
    gram_partial<<<64, 256, 0, stream>>>(xbuf, gpart);
    final_head<<<1, 256, 0, stream>>>(gpart, fc2_W, fc2_b, fco_W, fco_b,
                                      (float*)d_out);
}

// Round 4
// 700.018 us; speedup vs baseline: 1.5507x; 1.3046x over previous
//
#include <hip/hip_runtime.h>
#include <hip/hip_bf16.h>

// Problem constants (from reference)
#define BB 4096
#define VV 200
#define FF 4
#define GG 80
#define RR 16
#define NLIG 7
// f32(2*pi) = 0x40C90FDB; ANG_STEP = f32(2*pi)/16 exactly; 16*ANG_STEP == TWO_PI_F exactly
#define TWO_PI_F 6.2831853071795864769f
#define ANG_STEP 0.39269908169872414f
#define INV_ANG_STEP 2.5464790894703255f
#define LOG2E_F 1.4426950408889634f

__device__ __forceinline__ float fexp2(float x) {
#if __has_builtin(__builtin_amdgcn_exp2f)
    return __builtin_amdgcn_exp2f(x);   // raw v_exp_f32, 1 instr
#else
    return exp2f(x);
#endif
}

// j-space chain for a vertex of class C (j0 == C), compile-time C:
//   T[j] = M * B^j * K[j],  j = 0..15   (single chain, no wrap split)
//   rotation index r = (j - C) & 15  ->  agg[(j + 16 - C) & 15] += T[j]
template<int C>
__device__ __forceinline__ void cls_accum(float (&agg)[RR], const float (&K)[RR],
                                          float M, float B) {
    float u = M;
    #pragma unroll
    for (int j = 0; j < RR; ++j) {
        constexpr int dst0 = 0;  // silence unused warnings pattern
        (void)dst0;
        agg[(j + RR - C) & (RR - 1)] = fmaf(u, K[j], agg[(j + RR - C) & (RR - 1)]);
        if (j + 1 < RR) u *= B;
    }
}

// ---------------------------------------------------------------------------
// Kernel A: per-sample b. Vertices bucket-sorted by j0 (stable, deterministic);
// 16 class-loops with compile-time rotation -> branch-free inner loop with
// 1 mul + 1 fma per (v,r) and 2 exp2 per v. Then conv GEMV + relu + max over
// rotations, fc1 + relu. One block per b, 320 threads = (f,g).
// ---------------------------------------------------------------------------
__global__ __launch_bounds__(320) void masif_main(
    const float* __restrict__ xin,      // [B,V,F]
    const float* __restrict__ rho,      // [B,V]
    const float* __restrict__ theta,    // [B,V]
    const float* __restrict__ mask,     // [B,V]
    const float* __restrict__ mu_rho,   // [F,G]
    const float* __restrict__ mu_theta, // [F,G]
    const float* __restrict__ sigma_rho,   // [F,G]
    const float* __restrict__ sigma_theta, // [F,G]
    const float* __restrict__ conv_W,   // [F,G,G]
    const float* __restrict__ conv_b,   // [F,G]
    const float* __restrict__ fc1_W,    // [G, F*G]
    const float* __restrict__ fc1_b,    // [G]
    float* __restrict__ xbuf)           // [B,G] out
{
    const int b = blockIdx.x;
    const int t = threadIdx.x;
    const int f = t / GG;   // 0..3
    const int g = t % GG;   // 0..79

    __shared__ float2 pv_ra[VV];       // {rho, a0} sorted by class   1.6 KB
    __shared__ float  pv_x[FF][VV];    // mask*x   sorted by class    3.2 KB
    __shared__ int    jcls[VV];        // class per original vertex   0.8 KB
    __shared__ int    scls[RR + 1];    // class start offsets
    __shared__ float  aggL[FF][RR][GG];// 20.5 KB
    __shared__ float  desc_s[FF * GG]; // 1.3 KB
    __shared__ float  hp_s[FF][GG];    // 1.3 KB

    // ---- stage + bucket-sort vertices by j0 (stable -> deterministic) ----
    float rh = 0.0f, a0 = 0.0f, mx0 = 0.0f, mx1 = 0.0f, mx2 = 0.0f, mx3 = 0.0f;
    int j0 = 0;
    if (t < VV) {
        const int idx = b * VV + t;
        const float th = theta[idx];
        const float m  = mask[idx];
        rh = rho[idx];
        j0 = (int)(th * INV_ANG_STEP);
        if (j0 > RR - 1) j0 = RR - 1;               // guard th ~ 2*pi rounding
        a0 = fmaf(-(float)j0, ANG_STEP, th);        // th - j0*step, in [0, step)
        const float4 xv = *reinterpret_cast<const float4*>(&xin[idx * 4]);
        mx0 = m * xv.x; mx1 = m * xv.y; mx2 = m * xv.z; mx3 = m * xv.w;
        jcls[t] = j0;
    }
    __syncthreads();
    if (t < VV) {
        // stable rank: #{v' : key(v') < key(v)}, key = (class, original idx)
        int pos = 0;
        for (int v2 = 0; v2 < VV; ++v2) {
            const int k = jcls[v2];
            pos += (k < j0) || (k == j0 && v2 < t);
        }
        pv_ra[pos] = make_float2(rh, a0);
        pv_x[0][pos] = mx0; pv_x[1][pos] = mx1; pv_x[2][pos] = mx2; pv_x[3][pos] = mx3;
    } else if (t < VV + RR + 1) {
        const int c = t - VV;   // 0..16
        int cnt = 0;
        for (int v2 = 0; v2 < VV; ++v2) cnt += (jcls[v2] < c);
        scls[c] = cnt;
    }

    // per-(f,g) parameters (exp2-based: LOG2E folded into the scale consts)
    const float mr  = mu_rho[f * GG + g];
    const float mt  = mu_theta[f * GG + g];
    const float sr  = sigma_rho[f * GG + g];
    const float st  = sigma_theta[f * GG + g];
    const float nisr2 = -LOG2E_F / (sr * sr + 1e-5f);
    const float nist2 = -LOG2E_F / (st * st + 1e-5f);
    const float c1 = 2.0f * ANG_STEP * nist2;       // B(x) = 2^(c1*x)

    // static quadratic table K[m] = 2^(nist2 * Dlt^2 * m^2)  (16 regs)
    float K[RR];
    #pragma unroll
    for (int m = 0; m < RR; ++m)
        K[m] = fexp2(nist2 * (ANG_STEP * ANG_STEP) * (float)(m * m));

    __syncthreads();

    // ---- gaussian aggregation: 16 class-loops, branch-free bodies ----
    float agg[RR];
    #pragma unroll
    for (int r = 0; r < RR; ++r) agg[r] = 0.0f;

    int sprev = 0;
#define CLS(C) { \
        const int send = __builtin_amdgcn_readfirstlane(scls[(C) + 1]); \
        for (int v = sprev; v < send; ++v) { \
            const float2 ra = pv_ra[v]; \
            const float s  = pv_x[f][v]; \
            const float dr = ra.x - mr; \
            const float ar2 = (dr * dr) * nisr2; \
            const float x  = ra.y - mt; \
            const float M = fexp2(fmaf(x * x, nist2, ar2)) * s; \
            const float B = fexp2(x * c1); \
            cls_accum<(C)>(agg, K, M, B); \
        } \
        sprev = send; }
    CLS(0)  CLS(1)  CLS(2)  CLS(3)
    CLS(4)  CLS(5)  CLS(6)  CLS(7)
    CLS(8)  CLS(9)  CLS(10) CLS(11)
    CLS(12) CLS(13) CLS(14) CLS(15)
#undef CLS

    #pragma unroll
    for (int r = 0; r < RR; ++r) aggL[f][r][g] = agg[r];

    __syncthreads();

    // ---- conv GEMV + relu + max over rotations: thread = (f, j=g) ----
    float racc[RR];
    const float cb = conv_b[f * GG + g];
    #pragma unroll
    for (int r = 0; r < RR; ++r) racc[r] = cb;
    for (int g4 = 0; g4 < GG; g4 += 4) {
        const float w0 = conv_W[(f * GG + g4 + 0) * GG + g];
        const float w1 = conv_W[(f * GG + g4 + 1) * GG + g];
        const float w2 = conv_W[(f * GG + g4 + 2) * GG + g];
        const float w3 = conv_W[(f * GG + g4 + 3) * GG + g];
        #pragma unroll
        for (int r = 0; r < RR; ++r) {
            const float4 a4 = *reinterpret_cast<const float4*>(&aggL[f][r][g4]);
            float xx = racc[r];
            xx = fmaf(a4.x, w0, xx);
            xx = fmaf(a4.y, w1, xx);
            xx = fmaf(a4.z, w2, xx);
            xx = fmaf(a4.w, w3, xx);
            racc[r] = xx;
        }
    }
    float mxr = racc[0];
    #pragma unroll
    for (int r = 1; r < RR; ++r) mxr = fmaxf(mxr, racc[r]);
    desc_s[f * GG + g] = fmaxf(mxr, 0.0f);

    __syncthreads();

    // ---- fc1 + relu (80 outputs, dot over 320; 4-way k-split, all threads) --
    {
        const int p  = f;       // k-partial index 0..3
        const int jj = g;       // output index
        const float* wrow = &fc1_W[jj * (FF * GG) + p * GG];
        const float* drow = &desc_s[p * GG];
        float a = 0.0f;
        #pragma unroll 4
        for (int k = 0; k < GG; ++k) a = fmaf(drow[k], wrow[k], a);
        hp_s[p][jj] = a;
    }
    __syncthreads();
    if (t < GG) {
        float a1 = ((hp_s[0][t] + hp_s[1][t]) + (hp_s[2][t] + hp_s[3][t])) + fc1_b[t];
        xbuf[b * GG + t] = fmaxf(a1, 0.0f);
    }
}

// ---------------------------------------------------------------------------
// Kernel B: partial gram. 64 blocks x 64 samples each; 256 threads own 5x5
// tiles of the 80x80 outer-product accumulation. Deterministic.
// ---------------------------------------------------------------------------
__global__ __launch_bounds__(256) void gram_partial(
    const float* __restrict__ xbuf,   // [B,G]
    float* __restrict__ gpart)        // [64, G*G]
{
    const int blk = blockIdx.x;   // 0..63
    const int t = threadIdx.x;
    __shared__ float xs[64][GG];

    for (int i = t; i < 64 * GG; i += 256) {
        int bb = i / GG, jj = i % GG;
        xs[bb][jj] = xbuf[(blk * 64 + bb) * GG + jj];
    }
    __syncthreads();

    const int ti = t / 16, tj = t % 16;   // 16x16 grid of 5x5 tiles
    float acc[5][5];
    #pragma unroll
    for (int u = 0; u < 5; ++u)
        #pragma unroll
        for (int w = 0; w < 5; ++w) acc[u][w] = 0.0f;

    for (int bb = 0; bb < 64; ++bb) {
        float xi[5], xj[5];
        #pragma unroll
        for (int u = 0; u < 5; ++u) { xi[u] = xs[bb][ti * 5 + u]; xj[u] = xs[bb][tj * 5 + u]; }
        #pragma unroll
        for (int u = 0; u < 5; ++u)
            #pragma unroll
            for (int w = 0; w < 5; ++w)
                acc[u][w] = fmaf(xi[u], xj[w], acc[u][w]);
    }

    #pragma unroll
    for (int u = 0; u < 5; ++u)
        #pragma unroll
        for (int w = 0; w < 5; ++w)
            gpart[blk * (GG * GG) + (ti * 5 + u) * GG + (tj * 5 + w)] = acc[u][w];
}

// ---------------------------------------------------------------------------
// Kernel C: reduce gram partials (ordered -> deterministic), fc2+relu, fco.
// ---------------------------------------------------------------------------
__global__ __launch_bounds__(256) void final_head(
    const float* __restrict__ gpart,  // [64, G*G]
    const float* __restrict__ fc2_W,  // [64, G*G]
    const float* __restrict__ fc2_b,  // [64]
    const float* __restrict__ fco_W,  // [NLIG, 64]
    const float* __restrict__ fco_b,  // [NLIG]
    float* __restrict__ out)          // [NLIG]
{
    const int t = threadIdx.x;
    __shared__ float gram[GG * GG];   // 25.6 KB
    __shared__ float hp[4][64];
    __shared__ float h[64];

    for (int i = t; i < GG * GG; i += 256) {
        float s = 0.0f;
        for (int p = 0; p < 64; ++p) s += gpart[p * (GG * GG) + i];
        gram[i] = s * (1.0f / 4096.0f);
    }
    __syncthreads();

    {
        const int jj = t & 63, part = t >> 6;    // 4 partial splits over k
        float a = 0.0f;
        const int k0 = part * 1600, k1 = k0 + 1600;
        for (int k = k0; k < k1; ++k)
            a = fmaf(gram[k], fc2_W[jj * (GG * GG) + k], a);
        hp[part][jj] = a;
    }
    __syncthreads();
    if (t < 64)
        h[t] = fmaxf(hp[0][t] + hp[1][t] + hp[2][t] + hp[3][t] + fc2_b[t], 0.0f);
    __syncthreads();

    if (t < NLIG) {
        float a = fco_b[t];
        #pragma unroll
        for (int jj = 0; jj < 64; ++jj)
            a = fmaf(h[jj], fco_W[t * 64 + jj], a);
        out[t] = a;
    }
}

// ---------------------------------------------------------------------------
extern "C" void kernel_launch(void* const* d_in, const int* in_sizes, int n_in,
                              void* d_out, int out_size, void* d_ws, size_t ws_size,
                              hipStream_t stream) {
    const float* input_feat  = (const float*)d_in[0];
    const float* rho         = (const float*)d_in[1];
    const float* theta       = (const float*)d_in[2];
    const float* mask        = (const float*)d_in[3];
    const float* mu_rho      = (const float*)d_in[4];
    const float* mu_theta    = (const float*)d_in[5];
    const float* sigma_rho   = (const float*)d_in[6];
    const float* sigma_theta = (const float*)d_in[7];
    const float* conv_W      = (const float*)d_in[8];
    const float* conv_b      = (const float*)d_in[9];
    const float* fc1_W       = (const float*)d_in[10];
    const float* fc1_b       = (const float*)d_in[11];
    const float* fc2_W       = (const float*)d_in[12];
    const float* fc2_b       = (const float*)d_in[13];
    const float* fco_W       = (const float*)d_in[14];
    const float* fco_b       = (const float*)d_in[15];

    float* xbuf  = (float*)d_ws;                                    // [B,G]  1.31 MB
    float* gpart = (float*)((char*)d_ws + (size_t)BB * GG * 4);     // [64,G*G] 1.64 MB

    masif_main<<<BB, 320, 0, stream>>>(input_feat, rho, theta, mask,
                                       mu_rho, mu_theta, sigma_rho, sigma_theta,
                                       conv_W, conv_b, fc1_W, fc1_b, xbuf);
    gram_partial<<<64, 256, 0, stream>>>(xbuf, gpart);
    final_head<<<1, 256, 0, stream>>>(gpart, fc2_W, fc2_b, fco_W, fco_b,
                                      (float*)d_out);
}

// Round 5
// 364.957 us; speedup vs baseline: 2.9744x; 1.9181x over previous
//
#include <hip/hip_runtime.h>
#include <hip/hip_bf16.h>

// Problem constants (from reference)
#define BB 4096
#define VV 200
#define FF 4
#define GG 80
#define RR 16
#define NLIG 7
#define PVMAX 216   // 200 vertices + <=16 pad slots (even-aligned classes)
// f32(2*pi) = 0x40C90FDB; ANG_STEP = f32(2*pi)/16 exactly
#define TWO_PI_F 6.2831853071795864769f
#define ANG_STEP 0.39269908169872414f
#define INV_ANG_STEP 2.5464790894703255f
#define LOG2E_F 1.4426950408889634f

typedef float v2f __attribute__((ext_vector_type(2)));

__device__ __forceinline__ float fexp2(float x) {
#if __has_builtin(__builtin_amdgcn_exp2f)
    return __builtin_amdgcn_exp2f(x);   // raw v_exp_f32
#else
    return exp2f(x);
#endif
}

// packed f32 ops (VOP3P, CDNA2+): one instruction covers 2 lanes-worth of f32
__device__ __forceinline__ v2f pk_fma(v2f a, v2f b, v2f c) {
    v2f d;
    asm("v_pk_fma_f32 %0, %1, %2, %3" : "=v"(d) : "v"(a), "v"(b), "v"(c));
    return d;
}
__device__ __forceinline__ v2f pk_mul(v2f a, v2f b) {
    v2f d;
    asm("v_pk_mul_f32 %0, %1, %2" : "=v"(d) : "v"(a), "v"(b));
    return d;
}

// j-space chain for one vertex of class C (j0 == C):
//   T[j] = M * B^j * K[j], j = 0..15 ; contribution lands at r = (j - C) & 15.
// Even/odd j sub-chains (ratio B^2) packed into v2f; accumulate into
// aggE (even classes: pairs (r,r+1) aligned) or aggO (odd classes: pairs
// (r_odd, r_odd+1) i.e. aggO[k] = (r=2k+1, r=(2k+2)&15)). All indices static.
template<int C>
__device__ __forceinline__ void chain(const v2f (&Kp)[8], v2f (&aggE)[8],
                                      v2f (&aggO)[8], float M, float B) {
    const float B2 = B * B;
    v2f u;  u.x = M;  u.y = M * B;
    v2f w2; w2.x = B2; w2.y = B2;
    #pragma unroll
    for (int i = 0; i < 8; ++i) {
        const int idx = ((2 * i + 16 - C) & 15) >> 1;   // constant after unroll
        if constexpr ((C & 1) == 0) aggE[idx] = pk_fma(u, Kp[i], aggE[idx]);
        else                        aggO[idx] = pk_fma(u, Kp[i], aggO[idx]);
        if (i < 7) u = pk_mul(u, w2);
    }
}

// ---------------------------------------------------------------------------
// Kernel A: per-sample b. Vertices bucket-sorted by j0 with classes padded to
// even length (pad slots have s=0 -> exact no-op); 16 class-loops, unroll-2,
// packed-f32 chains. Then pk conv GEMV + relu + max, pk fc1 + relu.
// One block per b, 320 threads = (f,g).
// ---------------------------------------------------------------------------
__global__ __launch_bounds__(320, 6) void masif_main(
    const float* __restrict__ xin,      // [B,V,F]
    const float* __restrict__ rho,      // [B,V]
    const float* __restrict__ theta,    // [B,V]
    const float* __restrict__ mask,     // [B,V]
    const float* __restrict__ mu_rho,   // [F,G]
    const float* __restrict__ mu_theta, // [F,G]
    const float* __restrict__ sigma_rho,   // [F,G]
    const float* __restrict__ sigma_theta, // [F,G]
    const float* __restrict__ conv_W,   // [F,G,G]
    const float* __restrict__ conv_b,   // [F,G]
    const float* __restrict__ fc1_W,    // [G, F*G]
    const float* __restrict__ fc1_b,    // [G]
    float* __restrict__ xbuf)           // [B,G] out
{
    const int b = blockIdx.x;
    const int t = threadIdx.x;
    const int f = t / GG;   // 0..3
    const int g = t % GG;   // 0..79

    // union region: phase-1 {pv_ra, pv_x, jcls}; phase-2 {desc_s, hp_s}
    __shared__ __align__(16) char uni[PVMAX * 8 + FF * PVMAX * 4 + VV * 4];
    float2* pv_ra = reinterpret_cast<float2*>(uni);                       // [216]
    float (*pv_x)[PVMAX] = reinterpret_cast<float(*)[PVMAX]>(uni + PVMAX * 8);
    int* jcls = reinterpret_cast<int*>(uni + PVMAX * 8 + FF * PVMAX * 4); // [200]
    float* desc_s = reinterpret_cast<float*>(uni);                        // [320]
    float* hp_s   = reinterpret_cast<float*>(uni + 1280);                 // [4][80]

    __shared__ int cnt[RR];        // per-class counts
    __shared__ int ps[RR + 1];     // padded class starts (even)
    __shared__ float aggL[FF][RR][GG];  // 20.5 KB

    // ---- phase 0: classify ----
    float rh = 0.f, a0 = 0.f, mx0 = 0.f, mx1 = 0.f, mx2 = 0.f, mx3 = 0.f;
    int j0 = 0;
    if (t < VV) {
        const int idx = b * VV + t;
        const float th = theta[idx];
        const float m  = mask[idx];
        rh = rho[idx];
        j0 = (int)(th * INV_ANG_STEP);
        if (j0 > RR - 1) j0 = RR - 1;               // guard th ~ 2*pi rounding
        a0 = fmaf(-(float)j0, ANG_STEP, th);        // th - j0*step
        const float4 xv = *reinterpret_cast<const float4*>(&xin[idx * 4]);
        mx0 = m * xv.x; mx1 = m * xv.y; mx2 = m * xv.z; mx3 = m * xv.w;
        jcls[t] = j0;
    }

    // per-(f,g) params + packed K table (independent of staging phases)
    const float mr  = mu_rho[f * GG + g];
    const float mt  = mu_theta[f * GG + g];
    const float sr  = sigma_rho[f * GG + g];
    const float st  = sigma_theta[f * GG + g];
    const float nisr2 = -LOG2E_F / (sr * sr + 1e-5f);
    const float nist2 = -LOG2E_F / (st * st + 1e-5f);
    const float c1 = 2.0f * ANG_STEP * nist2;       // B(x) = 2^(c1*x)
    v2f Kp[8];
    #pragma unroll
    for (int i = 0; i < 8; ++i) {
        const float m0 = (float)(2 * i), m1 = (float)(2 * i + 1);
        Kp[i].x = fexp2(nist2 * (ANG_STEP * ANG_STEP) * m0 * m0);
        Kp[i].y = fexp2(nist2 * (ANG_STEP * ANG_STEP) * m1 * m1);
    }
    __syncthreads();

    // ---- phase A: stable rank within class + class counts + zero pv ----
    int rk = 0;
    if (t < VV) {
        for (int v2 = 0; v2 < VV; ++v2) {
            const int k = jcls[v2];
            rk += (k == j0 && v2 < t);
        }
    } else if (t < VV + RR) {
        const int c = t - VV;
        int cc = 0;
        for (int v2 = 0; v2 < VV; ++v2) cc += (jcls[v2] == c);
        cnt[c] = cc;
    }
    if (t < PVMAX) {
        pv_ra[t] = make_float2(0.f, 0.f);
        pv_x[0][t] = 0.f; pv_x[1][t] = 0.f; pv_x[2][t] = 0.f; pv_x[3][t] = 0.f;
    }
    __syncthreads();

    // ---- phase B: padded prefix (even class starts) ----
    if (t >= VV && t < VV + RR + 1) {
        const int c = t - VV;
        int s = 0;
        for (int c2 = 0; c2 < c; ++c2) s += (cnt[c2] + 1) & ~1;
        ps[c] = s;
    }
    __syncthreads();

    // ---- phase C: scatter ----
    if (t < VV) {
        const int pos = ps[j0] + rk;
        pv_ra[pos] = make_float2(rh, a0);
        pv_x[0][pos] = mx0; pv_x[1][pos] = mx1; pv_x[2][pos] = mx2; pv_x[3][pos] = mx3;
    }
    __syncthreads();

    // ---- gaussian aggregation: 16 class loops, pair-unrolled, pk chains ----
    v2f aggE[8], aggO[8];
    #pragma unroll
    for (int i = 0; i < 8; ++i) {
        aggE[i].x = 0.f; aggE[i].y = 0.f;
        aggO[i].x = 0.f; aggO[i].y = 0.f;
    }

    int sprev = 0;
#define CLS(C) { \
        const int send = __builtin_amdgcn_readfirstlane(ps[(C) + 1]); \
        for (int v = sprev; v < send; v += 2) { \
            const float4 ra2 = *reinterpret_cast<const float4*>(&pv_ra[v]); \
            const v2f s2 = *reinterpret_cast<const v2f*>(&pv_x[f][v]); \
            const float drA = ra2.x - mr, xA = ra2.y - mt; \
            const float arA = (drA * drA) * nisr2; \
            const float MA = fexp2(fmaf(xA * xA, nist2, arA)) * s2.x; \
            const float BA = fexp2(xA * c1); \
            const float drB = ra2.z - mr, xB = ra2.w - mt; \
            const float arB = (drB * drB) * nisr2; \
            const float MB = fexp2(fmaf(xB * xB, nist2, arB)) * s2.y; \
            const float BBv = fexp2(xB * c1); \
            chain<(C)>(Kp, aggE, aggO, MA, BA); \
            chain<(C)>(Kp, aggE, aggO, MB, BBv); \
        } \
        sprev = send; }
    CLS(0)  CLS(1)  CLS(2)  CLS(3)
    CLS(4)  CLS(5)  CLS(6)  CLS(7)
    CLS(8)  CLS(9)  CLS(10) CLS(11)
    CLS(12) CLS(13) CLS(14) CLS(15)
#undef CLS

    // combine dual accumulators -> r-space, write to LDS
    #pragma unroll
    for (int k = 0; k < 8; ++k) {
        aggL[f][2 * k][g]     = aggE[k].x + aggO[(k + 7) & 7].y;
        aggL[f][2 * k + 1][g] = aggE[k].y + aggO[k].x;
    }
    __syncthreads();

    // ---- conv GEMV (pk) + relu + max over rotations ----
    v2f racc2[RR];
    {
        const float cb = conv_b[f * GG + g];
        #pragma unroll
        for (int r = 0; r < RR; ++r) { racc2[r].x = cb; racc2[r].y = 0.f; }
    }
    for (int g4 = 0; g4 < GG; g4 += 4) {
        const float* wp = &conv_W[(f * GG + g4) * GG + g];
        v2f wA, wB;
        wA.x = wp[0];   wA.y = wp[GG];
        wB.x = wp[2 * GG]; wB.y = wp[3 * GG];
        #pragma unroll
        for (int r = 0; r < RR; ++r) {
            const float4 a4 = *reinterpret_cast<const float4*>(&aggL[f][r][g4]);
            v2f aA, aB;
            aA.x = a4.x; aA.y = a4.y;
            aB.x = a4.z; aB.y = a4.w;
            racc2[r] = pk_fma(aA, wA, racc2[r]);
            racc2[r] = pk_fma(aB, wB, racc2[r]);
        }
    }
    float mxr = racc2[0].x + racc2[0].y;
    #pragma unroll
    for (int r = 1; r < RR; ++r) mxr = fmaxf(mxr, racc2[r].x + racc2[r].y);
    desc_s[f * GG + g] = fmaxf(mxr, 0.0f);   // overlays pv region (pv is dead)

    __syncthreads();

    // ---- fc1 + relu (pk, 4-way k-split over f) ----
    {
        const v2f* wrow = reinterpret_cast<const v2f*>(&fc1_W[g * (FF * GG) + f * GG]);
        const v2f* drow = reinterpret_cast<const v2f*>(&desc_s[f * GG]);
        v2f a2; a2.x = 0.f; a2.y = 0.f;
        #pragma unroll 4
        for (int k = 0; k < GG / 2; ++k) a2 = pk_fma(drow[k], wrow[k], a2);
        hp_s[f * GG + g] = a2.x + a2.y;
    }
    __syncthreads();
    if (t < GG) {
        const float a1 = ((hp_s[t] + hp_s[GG + t]) + (hp_s[2 * GG + t] + hp_s[3 * GG + t]))
                         + fc1_b[t];
        xbuf[b * GG + t] = fmaxf(a1, 0.0f);
    }
}

// ---------------------------------------------------------------------------
// Kernel B: partial gram. 64 blocks x 64 samples; deterministic.
// ---------------------------------------------------------------------------
__global__ __launch_bounds__(256) void gram_partial(
    const float* __restrict__ xbuf,   // [B,G]
    float* __restrict__ gpart)        // [64, G*G]
{
    const int blk = blockIdx.x;
    const int t = threadIdx.x;
    __shared__ float xs[64][GG];

    for (int i = t; i < 64 * GG; i += 256) {
        int bb = i / GG, jj = i % GG;
        xs[bb][jj] = xbuf[(blk * 64 + bb) * GG + jj];
    }
    __syncthreads();

    const int ti = t / 16, tj = t % 16;
    float acc[5][5];
    #pragma unroll
    for (int u = 0; u < 5; ++u)
        #pragma unroll
        for (int w = 0; w < 5; ++w) acc[u][w] = 0.0f;

    for (int bb = 0; bb < 64; ++bb) {
        float xi[5], xj[5];
        #pragma unroll
        for (int u = 0; u < 5; ++u) { xi[u] = xs[bb][ti * 5 + u]; xj[u] = xs[bb][tj * 5 + u]; }
        #pragma unroll
        for (int u = 0; u < 5; ++u)
            #pragma unroll
            for (int w = 0; w < 5; ++w)
                acc[u][w] = fmaf(xi[u], xj[w], acc[u][w]);
    }

    #pragma unroll
    for (int u = 0; u < 5; ++u)
        #pragma unroll
        for (int w = 0; w < 5; ++w)
            gpart[blk * (GG * GG) + (ti * 5 + u) * GG + (tj * 5 + w)] = acc[u][w];
}

// ---------------------------------------------------------------------------
// Kernel C1: 64 blocks; block p owns k-range [p*100, p*100+100): reduce gram
// partials (ordered, deterministic) and compute partial fc2 dot products.
// ---------------------------------------------------------------------------
__global__ __launch_bounds__(128) void head_partial(
    const float* __restrict__ gpart,  // [64, G*G]
    const float* __restrict__ fc2_W,  // [64, G*G]
    float* __restrict__ hpp)          // [64, 64]
{
    const int p = blockIdx.x;   // 0..63
    const int t = threadIdx.x;
    __shared__ float gs[100];

    if (t < 100) {
        const int k = p * 100 + t;
        float s = 0.f;
        #pragma unroll 8
        for (int q = 0; q < 64; ++q) s += gpart[q * (GG * GG) + k];
        gs[t] = s * (1.0f / 4096.0f);
    }
    __syncthreads();
    if (t < 64) {
        const float* w = &fc2_W[t * (GG * GG) + p * 100];
        float a = 0.f;
        #pragma unroll 4
        for (int k = 0; k < 100; ++k) a = fmaf(gs[k], w[k], a);
        hpp[p * 64 + t] = a;
    }
}

// ---------------------------------------------------------------------------
// Kernel C2: reduce hpp (ordered), fc2 bias+relu, fco head.
// ---------------------------------------------------------------------------
__global__ __launch_bounds__(64) void head_final(
    const float* __restrict__ hpp,    // [64, 64]
    const float* __restrict__ fc2_b,  // [64]
    const float* __restrict__ fco_W,  // [NLIG, 64]
    const float* __restrict__ fco_b,  // [NLIG]
    float* __restrict__ out)          // [NLIG]
{
    const int t = threadIdx.x;
    __shared__ float hs[64];
    float a = 0.f;
    for (int p = 0; p < 64; ++p) a += hpp[p * 64 + t];
    hs[t] = fmaxf(a + fc2_b[t], 0.0f);
    __syncthreads();
    if (t < NLIG) {
        float o = fco_b[t];
        #pragma unroll
        for (int j = 0; j < 64; ++j) o = fmaf(hs[j], fco_W[t * 64 + j], o);
        out[t] = o;
    }
}

// ---------------------------------------------------------------------------
extern "C" void kernel_launch(void* const* d_in, const int* in_sizes, int n_in,
                              void* d_out, int out_size, void* d_ws, size_t ws_size,
                              hipStream_t stream) {
    const float* input_feat  = (const float*)d_in[0];
    const float* rho         = (const float*)d_in[1];
    const float* theta       = (const float*)d_in[2];
    const float* mask        = (const float*)d_in[3];
    const float* mu_rho      = (const float*)d_in[4];
    const float* mu_theta    = (const float*)d_in[5];
    const float* sigma_rho   = (const float*)d_in[6];
    const float* sigma_theta = (const float*)d_in[7];
    const float* conv_W      = (const float*)d_in[8];
    const float* conv_b      = (const float*)d_in[9];
    const float* fc1_W       = (const float*)d_in[10];
    const float* fc1_b       = (const float*)d_in[11];
    const float* fc2_W       = (const float*)d_in[12];
    const float* fc2_b       = (const float*)d_in[13];
    const float* fco_W       = (const float*)d_in[14];
    const float* fco_b       = (const float*)d_in[15];

    float* xbuf  = (float*)d_ws;                                      // [B,G]
    float* gpart = (float*)((char*)d_ws + (size_t)BB * GG * 4);       // [64,6400]
    float* hpp   = (float*)((char*)d_ws + (size_t)BB * GG * 4
                                        + (size_t)64 * GG * GG * 4);  // [64,64]

    masif_main<<<BB, 320, 0, stream>>>(input_feat, rho, theta, mask,
                                       mu_rho, mu_theta, sigma_rho, sigma_theta,
                                       conv_W, conv_b, fc1_W, fc1_b, xbuf);
    gram_partial<<<64, 256, 0, stream>>>(xbuf, gpart);
    head_partial<<<64, 128, 0, stream>>>(gpart, fc2_W, hpp);
    head_final<<<1, 64, 0, stream>>>(hpp, fc2_b, fco_W, fco_b, (float*)d_out);
}

// Round 6
// 317.283 us; speedup vs baseline: 3.4213x; 1.1503x over previous
//
#include <hip/hip_runtime.h>
#include <hip/hip_bf16.h>

// Problem constants (from reference)
#define BB 4096
#define VV 200
#define FF 4
#define GG 80
#define RR 16
#define NLIG 7
#define PVMAX 216   // 200 vertices + <=16 pad slots (even-aligned classes)
// f32(2*pi) = 0x40C90FDB; ANG_STEP = f32(2*pi)/16 exactly
#define TWO_PI_F 6.2831853071795864769f
#define ANG_STEP 0.39269908169872414f
#define INV_ANG_STEP 2.5464790894703255f
#define LOG2E_F 1.4426950408889634f

typedef float v2f __attribute__((ext_vector_type(2)));

__device__ __forceinline__ float fexp2(float x) {
#if __has_builtin(__builtin_amdgcn_exp2f)
    return __builtin_amdgcn_exp2f(x);   // raw v_exp_f32
#else
    return exp2f(x);
#endif
}

// packed f32 ops (VOP3P): one instruction, 2 f32 per lane (double-pumped 4cy)
__device__ __forceinline__ v2f pk_fma(v2f a, v2f b, v2f c) {
    v2f d;
    asm("v_pk_fma_f32 %0, %1, %2, %3" : "=v"(d) : "v"(a), "v"(b), "v"(c));
    return d;
}
__device__ __forceinline__ v2f pk_mul(v2f a, v2f b) {
    v2f d;
    asm("v_pk_mul_f32 %0, %1, %2" : "=v"(d) : "v"(a), "v"(b));
    return d;
}

// j-space chain for one vertex of class C (j0 == C):
//   T[j] = M * B^j * K[j], j = 0..15 ; contribution lands at r = (j - C) & 15.
// Even/odd j sub-chains (ratio B^2) packed into v2f; accumulate into
// aggE (even classes) or aggO (odd classes). All indices compile-time.
template<int C>
__device__ __forceinline__ void chain(const v2f (&Kp)[8], v2f (&aggE)[8],
                                      v2f (&aggO)[8], float M, float B) {
    const float B2 = B * B;
    v2f u;  u.x = M;  u.y = M * B;
    v2f w2; w2.x = B2; w2.y = B2;
    #pragma unroll
    for (int i = 0; i < 8; ++i) {
        const int idx = ((2 * i + 16 - C) & 15) >> 1;   // constant after unroll
        if constexpr ((C & 1) == 0) aggE[idx] = pk_fma(u, Kp[i], aggE[idx]);
        else                        aggO[idx] = pk_fma(u, Kp[i], aggO[idx]);
        if (i < 7) u = pk_mul(u, w2);
    }
}

// ---------------------------------------------------------------------------
// Kernel A: per-sample b. Masked vertices dropped (exact: they contribute
// +-0 to every sum). Kept vertices bucket-sorted by j0 via wave-ballot
// counting sort (O(16) instead of O(V^2)); classes padded even (pad slots
// s=0 -> exact no-op). 16 class-loops, pair-unrolled packed-f32 chains.
// Then pk conv GEMV + relu + max, pk fc1 + relu. One block per b, 320 thr.
// ---------------------------------------------------------------------------
__global__ __launch_bounds__(320, 6) void masif_main(
    const float* __restrict__ xin,      // [B,V,F]
    const float* __restrict__ rho,      // [B,V]
    const float* __restrict__ theta,    // [B,V]
    const float* __restrict__ mask,     // [B,V]
    const float* __restrict__ mu_rho,   // [F,G]
    const float* __restrict__ mu_theta, // [F,G]
    const float* __restrict__ sigma_rho,   // [F,G]
    const float* __restrict__ sigma_theta, // [F,G]
    const float* __restrict__ conv_W,   // [F,G,G]
    const float* __restrict__ conv_b,   // [F,G]
    const float* __restrict__ fc1_W,    // [G, F*G]
    const float* __restrict__ fc1_b,    // [G]
    float* __restrict__ xbuf)           // [B,G] out
{
    const int b = blockIdx.x;
    const int t = threadIdx.x;
    const int f = t / GG;    // 0..3
    const int g = t % GG;    // 0..79
    const int lane = t & 63;
    const int w = t >> 6;    // wave 0..4

    // union region: phase-1 {pv_ra, pv_x}; phase-2 {desc_s, hp_s}
    __shared__ __align__(16) char uni[PVMAX * 8 + FF * PVMAX * 4];
    float2* pv_ra = reinterpret_cast<float2*>(uni);                     // [216]
    float (*pv_x)[PVMAX] = reinterpret_cast<float(*)[PVMAX]>(uni + PVMAX * 8);
    float* desc_s = reinterpret_cast<float*>(uni);                      // [320]
    float* hp_s   = reinterpret_cast<float*>(uni + 1280);               // [4][80]

    __shared__ int cntw[5][RR];    // per-wave per-class counts
    __shared__ int ps[RR + 1];     // padded class starts (even)
    __shared__ float aggL[FF][RR][GG];  // 20.5 KB

    // ---- phase 0: classify (masked vertices dropped: exact zeros) ----
    float rh = 0.f, a0 = 0.f, mx0 = 0.f, mx1 = 0.f, mx2 = 0.f, mx3 = 0.f;
    int j0 = 0;
    bool keep = false;
    if (t < VV) {
        const int idx = b * VV + t;
        const float th = theta[idx];
        const float m  = mask[idx];
        keep = (m != 0.0f);
        rh = rho[idx];
        j0 = (int)(th * INV_ANG_STEP);
        if (j0 > RR - 1) j0 = RR - 1;               // guard th ~ 2*pi rounding
        a0 = fmaf(-(float)j0, ANG_STEP, th);        // th - j0*step
        const float4 xv = *reinterpret_cast<const float4*>(&xin[idx * 4]);
        mx0 = m * xv.x; mx1 = m * xv.y; mx2 = m * xv.z; mx3 = m * xv.w;
    }

    // per-(f,g) params + packed K table (no LDS deps)
    const float mr  = mu_rho[f * GG + g];
    const float mt  = mu_theta[f * GG + g];
    const float sr  = sigma_rho[f * GG + g];
    const float st  = sigma_theta[f * GG + g];
    const float nisr2 = -LOG2E_F / (sr * sr + 1e-5f);
    const float nist2 = -LOG2E_F / (st * st + 1e-5f);
    const float c1 = 2.0f * ANG_STEP * nist2;       // B(x) = 2^(c1*x)
    v2f Kp[8];
    #pragma unroll
    for (int i = 0; i < 8; ++i) {
        const float m0 = (float)(2 * i), m1 = (float)(2 * i + 1);
        Kp[i].x = fexp2(nist2 * (ANG_STEP * ANG_STEP) * m0 * m0);
        Kp[i].y = fexp2(nist2 * (ANG_STEP * ANG_STEP) * m1 * m1);
    }

    // ---- ballot counting sort: rank-in-wave + per-wave class counts ----
    int rank = 0, cnt_lane = 0;
    #pragma unroll
    for (int c = 0; c < RR; ++c) {
        const unsigned long long mbl = __ballot(keep && (j0 == c));
        if (keep && (j0 == c))
            rank = (int)__popcll(mbl & ((1ull << lane) - 1ull));
        if (lane == c) cnt_lane = (int)__popcll(mbl);
    }
    if (lane < RR) cntw[w][lane] = cnt_lane;
    __syncthreads();   // B1: cntw ready

    // t0: padded prefix; all others: zero-fill pv (pads -> exact no-ops)
    if (t == 0) {
        int s = 0;
        #pragma unroll
        for (int c = 0; c < RR; ++c) {
            ps[c] = s;
            const int cc = cntw[0][c] + cntw[1][c] + cntw[2][c]
                         + cntw[3][c] + cntw[4][c];
            s += (cc + 1) & ~1;
        }
        ps[RR] = s;
    }
    if (t < PVMAX) {
        pv_ra[t] = make_float2(0.f, 0.f);
        pv_x[0][t] = 0.f; pv_x[1][t] = 0.f; pv_x[2][t] = 0.f; pv_x[3][t] = 0.f;
    }
    __syncthreads();   // B2: ps + zero-fill ready

    // scatter kept vertices (stable within class -> deterministic)
    if (keep) {
        int off = 0;
        #pragma unroll
        for (int w2 = 0; w2 < 4; ++w2)
            if (w2 < w) off += cntw[w2][j0];
        const int pos = ps[j0] + off + rank;
        pv_ra[pos] = make_float2(rh, a0);
        pv_x[0][pos] = mx0; pv_x[1][pos] = mx1;
        pv_x[2][pos] = mx2; pv_x[3][pos] = mx3;
    }
    __syncthreads();   // B3: pv ready

    // ---- gaussian aggregation: 16 class loops, pair-unrolled, pk chains ----
    v2f aggE[8], aggO[8];
    #pragma unroll
    for (int i = 0; i < 8; ++i) {
        aggE[i].x = 0.f; aggE[i].y = 0.f;
        aggO[i].x = 0.f; aggO[i].y = 0.f;
    }

    int sprev = 0;
#define CLS(C) { \
        const int send = __builtin_amdgcn_readfirstlane(ps[(C) + 1]); \
        for (int v = sprev; v < send; v += 2) { \
            const float4 ra2 = *reinterpret_cast<const float4*>(&pv_ra[v]); \
            const v2f s2 = *reinterpret_cast<const v2f*>(&pv_x[f][v]); \
            const float drA = ra2.x - mr, xA = ra2.y - mt; \
            const float arA = (drA * drA) * nisr2; \
            const float MA = fexp2(fmaf(xA * xA, nist2, arA)) * s2.x; \
            const float BA = fexp2(xA * c1); \
            const float drB = ra2.z - mr, xB = ra2.w - mt; \
            const float arB = (drB * drB) * nisr2; \
            const float MB = fexp2(fmaf(xB * xB, nist2, arB)) * s2.y; \
            const float BBv = fexp2(xB * c1); \
            chain<(C)>(Kp, aggE, aggO, MA, BA); \
            chain<(C)>(Kp, aggE, aggO, MB, BBv); \
        } \
        sprev = send; }
    CLS(0)  CLS(1)  CLS(2)  CLS(3)
    CLS(4)  CLS(5)  CLS(6)  CLS(7)
    CLS(8)  CLS(9)  CLS(10) CLS(11)
    CLS(12) CLS(13) CLS(14) CLS(15)
#undef CLS

    // combine dual accumulators -> r-space, write to LDS
    #pragma unroll
    for (int k = 0; k < 8; ++k) {
        aggL[f][2 * k][g]     = aggE[k].x + aggO[(k + 7) & 7].y;
        aggL[f][2 * k + 1][g] = aggE[k].y + aggO[k].x;
    }
    __syncthreads();   // B4: aggL ready (pv region now dead)

    // ---- conv GEMV (pk) + relu + max over rotations ----
    v2f racc2[RR];
    {
        const float cb = conv_b[f * GG + g];
        #pragma unroll
        for (int r = 0; r < RR; ++r) { racc2[r].x = cb; racc2[r].y = 0.f; }
    }
    for (int g4 = 0; g4 < GG; g4 += 4) {
        const float* wp = &conv_W[(f * GG + g4) * GG + g];
        v2f wA, wB;
        wA.x = wp[0];      wA.y = wp[GG];
        wB.x = wp[2 * GG]; wB.y = wp[3 * GG];
        #pragma unroll
        for (int r = 0; r < RR; ++r) {
            const float4 a4 = *reinterpret_cast<const float4*>(&aggL[f][r][g4]);
            v2f aA, aB;
            aA.x = a4.x; aA.y = a4.y;
            aB.x = a4.z; aB.y = a4.w;
            racc2[r] = pk_fma(aA, wA, racc2[r]);
            racc2[r] = pk_fma(aB, wB, racc2[r]);
        }
    }
    float mxr = racc2[0].x + racc2[0].y;
    #pragma unroll
    for (int r = 1; r < RR; ++r) mxr = fmaxf(mxr, racc2[r].x + racc2[r].y);
    desc_s[f * GG + g] = fmaxf(mxr, 0.0f);   // overlays pv region (dead)

    __syncthreads();   // B5: desc ready

    // ---- fc1 + relu (pk, 4-way k-split over f) ----
    {
        const v2f* wrow = reinterpret_cast<const v2f*>(&fc1_W[g * (FF * GG) + f * GG]);
        const v2f* drow = reinterpret_cast<const v2f*>(&desc_s[f * GG]);
        v2f a2; a2.x = 0.f; a2.y = 0.f;
        #pragma unroll 4
        for (int k = 0; k < GG / 2; ++k) a2 = pk_fma(drow[k], wrow[k], a2);
        hp_s[f * GG + g] = a2.x + a2.y;
    }
    __syncthreads();   // B6: hp ready
    if (t < GG) {
        const float a1 = ((hp_s[t] + hp_s[GG + t]) + (hp_s[2 * GG + t] + hp_s[3 * GG + t]))
                         + fc1_b[t];
        xbuf[b * GG + t] = fmaxf(a1, 0.0f);
    }
}

// ---------------------------------------------------------------------------
// Kernel B: partial gram. 64 blocks x 64 samples; deterministic.
// ---------------------------------------------------------------------------
__global__ __launch_bounds__(256) void gram_partial(
    const float* __restrict__ xbuf,   // [B,G]
    float* __restrict__ gpart)        // [64, G*G]
{
    const int blk = blockIdx.x;
    const int t = threadIdx.x;
    __shared__ float xs[64][GG];

    for (int i = t; i < 64 * GG; i += 256) {
        int bb = i / GG, jj = i % GG;
        xs[bb][jj] = xbuf[(blk * 64 + bb) * GG + jj];
    }
    __syncthreads();

    const int ti = t / 16, tj = t % 16;
    float acc[5][5];
    #pragma unroll
    for (int u = 0; u < 5; ++u)
        #pragma unroll
        for (int w = 0; w < 5; ++w) acc[u][w] = 0.0f;

    for (int bb = 0; bb < 64; ++bb) {
        float xi[5], xj[5];
        #pragma unroll
        for (int u = 0; u < 5; ++u) { xi[u] = xs[bb][ti * 5 + u]; xj[u] = xs[bb][tj * 5 + u]; }
        #pragma unroll
        for (int u = 0; u < 5; ++u)
            #pragma unroll
            for (int w = 0; w < 5; ++w)
                acc[u][w] = fmaf(xi[u], xj[w], acc[u][w]);
    }

    #pragma unroll
    for (int u = 0; u < 5; ++u)
        #pragma unroll
        for (int w = 0; w < 5; ++w)
            gpart[blk * (GG * GG) + (ti * 5 + u) * GG + (tj * 5 + w)] = acc[u][w];
}

// ---------------------------------------------------------------------------
// Kernel C1: 64 blocks; block p owns k-range [p*100, p*100+100): reduce gram
// partials (ordered, deterministic) and compute partial fc2 dot products.
// ---------------------------------------------------------------------------
__global__ __launch_bounds__(128) void head_partial(
    const float* __restrict__ gpart,  // [64, G*G]
    const float* __restrict__ fc2_W,  // [64, G*G]
    float* __restrict__ hpp)          // [64, 64]
{
    const int p = blockIdx.x;   // 0..63
    const int t = threadIdx.x;
    __shared__ float gs[100];

    if (t < 100) {
        const int k = p * 100 + t;
        float s = 0.f;
        #pragma unroll 8
        for (int q = 0; q < 64; ++q) s += gpart[q * (GG * GG) + k];
        gs[t] = s * (1.0f / 4096.0f);
    }
    __syncthreads();
    if (t < 64) {
        const float* w = &fc2_W[t * (GG * GG) + p * 100];
        float a = 0.f;
        #pragma unroll 4
        for (int k = 0; k < 100; ++k) a = fmaf(gs[k], w[k], a);
        hpp[p * 64 + t] = a;
    }
}

// ---------------------------------------------------------------------------
// Kernel C2: reduce hpp (ordered), fc2 bias+relu, fco head. 256 threads:
// 4-way split over partials, then combine.
// ---------------------------------------------------------------------------
__global__ __launch_bounds__(256) void head_final(
    const float* __restrict__ hpp,    // [64, 64]
    const float* __restrict__ fc2_b,  // [64]
    const float* __restrict__ fco_W,  // [NLIG, 64]
    const float* __restrict__ fco_b,  // [NLIG]
    float* __restrict__ out)          // [NLIG]
{
    const int t = threadIdx.x;
    const int part = t >> 6, j = t & 63;
    __shared__ float hq[4][64];
    __shared__ float hs[64];
    float a = 0.f;
    #pragma unroll 4
    for (int p = part * 16; p < part * 16 + 16; ++p) a += hpp[p * 64 + j];
    hq[part][j] = a;
    __syncthreads();
    if (t < 64)
        hs[t] = fmaxf(((hq[0][t] + hq[1][t]) + (hq[2][t] + hq[3][t])) + fc2_b[t], 0.0f);
    __syncthreads();
    if (t < NLIG) {
        float o = fco_b[t];
        #pragma unroll
        for (int jj = 0; jj < 64; ++jj) o = fmaf(hs[jj], fco_W[t * 64 + jj], o);
        out[t] = o;
    }
}

// ---------------------------------------------------------------------------
extern "C" void kernel_launch(void* const* d_in, const int* in_sizes, int n_in,
                              void* d_out, int out_size, void* d_ws, size_t ws_size,
                              hipStream_t stream) {
    const float* input_feat  = (const float*)d_in[0];
    const float* rho         = (const float*)d_in[1];
    const float* theta       = (const float*)d_in[2];
    const float* mask        = (const float*)d_in[3];
    const float* mu_rho      = (const float*)d_in[4];
    const float* mu_theta    = (const float*)d_in[5];
    const float* sigma_rho   = (const float*)d_in[6];
    const float* sigma_theta = (const float*)d_in[7];
    const float* conv_W      = (const float*)d_in[8];
    const float* conv_b      = (const float*)d_in[9];
    const float* fc1_W       = (const float*)d_in[10];
    const float* fc1_b       = (const float*)d_in[11];
    const float* fc2_W       = (const float*)d_in[12];
    const float* fc2_b       = (const float*)d_in[13];
    const float* fco_W       = (const float*)d_in[14];
    const float* fco_b       = (const float*)d_in[15];

    float* xbuf  = (float*)d_ws;                                      // [B,G]
    float* gpart = (float*)((char*)d_ws + (size_t)BB * GG * 4);       // [64,6400]
    float* hpp   = (float*)((char*)d_ws + (size_t)BB * GG * 4
                                        + (size_t)64 * GG * GG * 4);  // [64,64]

    masif_main<<<BB, 320, 0, stream>>>(input_feat, rho, theta, mask,
                                       mu_rho, mu_theta, sigma_rho, sigma_theta,
                                       conv_W, conv_b, fc1_W, fc1_b, xbuf);
    gram_partial<<<64, 256, 0, stream>>>(xbuf, gpart);
    head_partial<<<64, 128, 0, stream>>>(gpart, fc2_W, hpp);
    head_final<<<1, 256, 0, stream>>>(hpp, fc2_b, fco_W, fco_b, (float*)d_out);
}